// Round 2
// baseline (213.292 us; speedup 1.0000x reference)
//
#include <hip/hip_runtime.h>
#include <cmath>

// CapsuleLayer routing, B=64, Ni=2048, Di=16, No=32, Do=16 (fp32 in/out).
// R6: fused plan (R5) + three levers:
//  (1) v_cvt_pk_bf16_f32 staging: split4 is 12 insts instead of ~50.
//  (2) 4-way b-split (grid 1024 = 256 ng x 4 bq, 16 b per block): 32 waves/CU
//      (4 blocks x 8 waves) so the 3-barrier/iter structure is hidden by
//      cross-block overlap. Per-wave tile 16b x 4o -> Dv+sacc = 32 VGPR,
//      fits the 64-VGPR cap for 8 waves/SIMD.
//  (3) pad-free XOR-swizzled LDS (rows = 8 dwords, 16B unit ^= (row>>2)&1):
//      b128 frag reads <=2-way bank aliasing (free), LDS 38.1 KB -> 4 blocks/CU.
// W is read once from HBM per XCD (4 bq blocks of an ng pinned to one XCD).

#define NI 2048

typedef short bf16x8 __attribute__((ext_vector_type(8)));
typedef float f32x4 __attribute__((ext_vector_type(4)));

static __device__ __forceinline__ unsigned cvt_pk_bf16(float a, float b) {
  unsigned r;
  asm("v_cvt_pk_bf16_f32 %0, %1, %2" : "=v"(r) : "v"(a), "v"(b));
  return r;  // lo16 = bf16(a), hi16 = bf16(b), RNE
}
// fp32 -> (hi bf16x4, lo bf16x4) with hi+lo ~ full precision
static __device__ __forceinline__ void split4_pk(float4 v, uint2& hi, uint2& lo) {
  hi.x = cvt_pk_bf16(v.x, v.y);
  hi.y = cvt_pk_bf16(v.z, v.w);
  float r0 = v.x - __uint_as_float(hi.x << 16);
  float r1 = v.y - __uint_as_float(hi.x & 0xFFFF0000u);
  float r2 = v.z - __uint_as_float(hi.y << 16);
  float r3 = v.w - __uint_as_float(hi.y & 0xFFFF0000u);
  lo.x = cvt_pk_bf16(r0, r1);
  lo.y = cvt_pk_bf16(r2, r3);
}
// dword offset of 16B unit u (0/1) of row r in a rows-of-8-dwords array,
// XOR-swizzled so stride-8 row reads spread across banks (both sides use it).
static __device__ __forceinline__ int swz8(int r, int u) {
  return r * 8 + ((u ^ ((r >> 2) & 1)) << 2);
}

// ---------------- Fused kernel: MFMA + in-block routing + weighted accumulate ----
// grid 1024; xcd = bx&7, slot = bx>>3; ng = xcd*32 + (slot>>2); bq = slot&3
// (all 4 bq blocks of an ng on one XCD -> W read once per XCD from L2/L3).
// block 512 = 8 waves; wave wv owns o = wv*4 .. wv*4+3, all 16 b of the bq.
// A = [W_hi|W_lo] (m=d, K=32 packed split), B = [x_hi],[x_lo] dup along K.
// LDS dword offsets (rows of 8 dwords, swizzled):
#define WAOFF 0       // 32 o * 32 rows (s*16+d) * 8 = 8192
#define XBOFF 8192    // 32 rows (s*16+b_local) * 8 = 256
#define HOFF  8448    // h[b_local][o]: 16 * 33 = 528
#define C2OFF 8976    // c2[o][b_local]: 32 * 17 = 544
#define LDSZ  9520    // 38.1 KB -> 4 blocks/CU
__global__ __launch_bounds__(512, 8) void caps_fused_kernel(
    const float* __restrict__ x, const float* __restrict__ W,
    float* __restrict__ partial)
{
  const int bx = blockIdx.x;
  const int xcd = bx & 7, slot = bx >> 3;
  const int ng = xcd * 32 + (slot >> 2);
  const int bq = slot & 3;
  const int t = threadIdx.x;
  const int wv = t >> 6, l = t & 63;
  const int q = l >> 4, dq = l & 15, qh = q & 1, s_a = q >> 1;

  __shared__ __align__(16) float lds[LDSZ];
  float* WA  = lds + WAOFF;
  float* XB  = lds + XBOFF;
  float* hS  = lds + HOFF;
  float* c2S = lds + C2OFF;

  float sacc[4][4];
  #pragma unroll
  for (int oo = 0; oo < 4; ++oo)
    { sacc[oo][0] = 0.f; sacc[oo][1] = 0.f; sacc[oo][2] = 0.f; sacc[oo][3] = 0.f; }

  const int n0 = ng * 8;
  // staging decompositions: W chunk c covers o = c*8 + wv; (d, i4) from t
  const int wd = (t >> 2) & 15, wi4 = t & 3;
  const int wu = wi4 >> 1, wsub = (wi4 & 1) * 2;
  const int xb = t >> 2, xi4 = t & 3;          // x staging: t < 64 only
  const int xu = xi4 >> 1, xsub = (xi4 & 1) * 2;

  // initial global loads (full W[n]: 4 chunks of 8 o's; x: 16 b x 16 i)
  float4 wreg[4];
  #pragma unroll
  for (int c = 0; c < 4; ++c)
    wreg[c] = *(const float4*)(W + (size_t)n0 * 8192 + c * 2048 + 4 * t);
  float4 xreg = make_float4(0.f, 0.f, 0.f, 0.f);
  if (t < 64)
    xreg = *(const float4*)(x + (size_t)(bq * 16 + xb) * (NI * 16) + n0 * 16 + xi4 * 4);

  #pragma unroll 1
  for (int nn = 0; nn < 8; ++nn) {
    // ---- stage: cvt_pk split to bf16, swizzled LDS writes ----
    #pragma unroll
    for (int c = 0; c < 4; ++c) {
      uint2 hi, lo;
      split4_pk(wreg[c], hi, lo);
      const int rh = (c * 8 + wv) * 32 + wd;     // hi row (s=0)
      *(uint2*)&WA[swz8(rh, wu) + wsub] = hi;
      *(uint2*)&WA[swz8(rh + 16, wu) + wsub] = lo;
    }
    if (t < 64) {
      uint2 hi, lo;
      split4_pk(xreg, hi, lo);
      *(uint2*)&XB[swz8(xb, xu) + xsub] = hi;
      *(uint2*)&XB[swz8(16 + xb, xu) + xsub] = lo;
    }
    __syncthreads();   // sync1: LDS staged

    // ---- prefetch next n (overlaps MFMA + routing below) ----
    if (nn < 7) {
      const size_t nb = (size_t)(n0 + nn + 1);
      #pragma unroll
      for (int c = 0; c < 4; ++c)
        wreg[c] = *(const float4*)(W + nb * 8192 + c * 2048 + 4 * t);
      if (t < 64)
        xreg = *(const float4*)(x + (size_t)(bq * 16 + xb) * (NI * 16) + nb * 16 + xi4 * 4);
    }

    // ---- MFMA: D retained per o; h = row-sum(D) -> LDS ----
    f32x4 Dv[4];
    {
      bf16x8 B0 = *(const bf16x8*)&XB[swz8(dq, qh)];        // x_hi
      bf16x8 B1 = *(const bf16x8*)&XB[swz8(16 + dq, qh)];   // x_lo
      #pragma unroll
      for (int oo = 0; oo < 4; ++oo) {
        const int o = wv * 4 + oo;
        bf16x8 A = *(const bf16x8*)&WA[swz8(o * 32 + s_a * 16 + dq, qh)];
        f32x4 D = {0.f, 0.f, 0.f, 0.f};
        D = __builtin_amdgcn_mfma_f32_16x16x32_bf16(A, B0, D, 0, 0, 0);
        D = __builtin_amdgcn_mfma_f32_16x16x32_bf16(A, B1, D, 0, 0, 0);
        Dv[oo] = D;
        float hs = D[0] + D[1] + D[2] + D[3];   // sum over d within q-group
        hs += __shfl_xor(hs, 16);
        hs += __shfl_xor(hs, 32);               // sum over q
        if (q == 0) hS[dq * 33 + o] = hs;
      }
    }
    __syncthreads();   // sync2: h complete

    // ---- routing (proven math): one (b_local, o) per thread,
    //      softmax over o via 5-level xor-shuffle (o = lane bits 0..4) ----
    {
      const int bl = t >> 5, o = t & 31;
      const float h = hS[bl * 33 + o];
      const float b1 = h * 0.03125f;
      float mx = b1;
      mx = fmaxf(mx, __shfl_xor(mx, 1));  mx = fmaxf(mx, __shfl_xor(mx, 2));
      mx = fmaxf(mx, __shfl_xor(mx, 4));  mx = fmaxf(mx, __shfl_xor(mx, 8));
      mx = fmaxf(mx, __shfl_xor(mx, 16));
      const float e = __expf(b1 - mx);
      float S = e;
      S += __shfl_xor(S, 1); S += __shfl_xor(S, 2);
      S += __shfl_xor(S, 4); S += __shfl_xor(S, 8); S += __shfl_xor(S, 16);
      const float b2 = b1 + e * (1.0f / S) * h;
      float mx2 = b2;
      mx2 = fmaxf(mx2, __shfl_xor(mx2, 1));  mx2 = fmaxf(mx2, __shfl_xor(mx2, 2));
      mx2 = fmaxf(mx2, __shfl_xor(mx2, 4));  mx2 = fmaxf(mx2, __shfl_xor(mx2, 8));
      mx2 = fmaxf(mx2, __shfl_xor(mx2, 16));
      const float e2 = __expf(b2 - mx2);
      float S2 = e2;
      S2 += __shfl_xor(S2, 1); S2 += __shfl_xor(S2, 2);
      S2 += __shfl_xor(S2, 4); S2 += __shfl_xor(S2, 8); S2 += __shfl_xor(S2, 16);
      c2S[o * 17 + bl] = e2 * (1.0f / S2);
    }
    __syncthreads();   // sync3: c2 ready

    // ---- weighted accumulate from retained D (no second MFMA pass) ----
    #pragma unroll
    for (int oo = 0; oo < 4; ++oo) {
      const int o = wv * 4 + oo;
      const float c = c2S[o * 17 + dq];
      sacc[oo][0] += c * Dv[oo][0]; sacc[oo][1] += c * Dv[oo][1];
      sacc[oo][2] += c * Dv[oo][2]; sacc[oo][3] += c * Dv[oo][3];
    }
    // no sync needed: next stage writes WA/XB (last read before sync2);
    // c2S next written only after next sync2.
  }

  // ---- epilogue: gidx-major, block-contiguous (proven clean-WRITE layout) ----
  // partial[ng][b_global][cell], cell = o*16 + d, d = q*4 + r
  float* pb = partial + (size_t)ng * 32768
            + (size_t)(bq * 16 + dq) * 512 + q * 4;
  #pragma unroll
  for (int oo = 0; oo < 4; ++oo) {
    const int o = wv * 4 + oo;
    *(float4*)(pb + o * 16)
        = make_float4(sacc[oo][0], sacc[oo][1], sacc[oo][2], sacc[oo][3]);
  }
}

// ---------------- Kernel 2: reduce 256 group-partials + squash (unchanged) ----
__global__ __launch_bounds__(256) void caps_reduce_kernel(
    const float* __restrict__ partial, float* __restrict__ out)
{
  const int t = threadIdx.x;
  const int w4 = t >> 6, ln = t & 63;
  const int pair = blockIdx.x * 4 + w4;     // (b,o), 2048 total
  const int b = pair >> 5, o = pair & 31;
  const int d = ln & 15, cg = ln >> 4;
  const float* p = partial + (size_t)b * 512 + o * 16 + d;
  float s = 0.f;
  #pragma unroll 8
  for (int gg = cg; gg < 256; gg += 4) s += p[(size_t)gg * 32768];
  s += __shfl_xor(s, 16); s += __shfl_xor(s, 32);    // over cg
  float s2 = s * s;
  s2 += __shfl_xor(s2, 1); s2 += __shfl_xor(s2, 2);
  s2 += __shfl_xor(s2, 4); s2 += __shfl_xor(s2, 8);  // over d
  float scale = s2 / (1.0f + s2) / sqrtf(s2 + 1e-7f);
  if (ln < 16) out[(size_t)b * 512 + o * 16 + d] = scale * s;
}

extern "C" void kernel_launch(void* const* d_in, const int* in_sizes, int n_in,
                              void* d_out, int out_size, void* d_ws, size_t ws_size,
                              hipStream_t stream) {
  const float* x = (const float*)d_in[0];   // [64,2048,16]
  const float* W = (const float*)d_in[1];   // [1,2048,32,16,16]
  if (in_sizes[0] != 64 * 2048 * 16) { const float* tmp = x; x = W; W = tmp; }
  float* out = (float*)d_out;               // [64,32,16]

  float* partial = (float*)d_ws;            // 256*32768 f32 = 32 MB (gidx-major)

  caps_fused_kernel<<<1024, 512, 0, stream>>>(x, W, partial);
  caps_reduce_kernel<<<512, 256, 0, stream>>>(partial, out);
}

// Round 3
// 163.720 us; speedup vs baseline: 1.3028x; 1.3028x over previous
//
#include <hip/hip_runtime.h>
#include <cmath>

// CapsuleLayer routing, B=64, Ni=2048, Di=16, No=32, Do=16 (fp32 in/out).
// R7 = R6 with the register budget fixed. R6's post-mortem: __launch_bounds__
// (512,8) capped unified VGPR+AGPR at 64/wave; kernel needs ~80 -> compiler
// allocated 32 VGPRs and spilled accumulators to scratch (FETCH 37->203 MB,
// WRITE 33->194 MB, fused 42->127 us). R6's other levers all verified:
// bank conflicts 2.69M -> 0 (XOR swizzle), cvt_pk staging, 4-way b-split.
//  (512,6): 6 waves/SIMD -> ~84-reg cap, fits ~80-reg need, 3 blocks/CU
//  = 24 waves/CU (vs R5's 16) for barrier hiding.

#define NI 2048

typedef short bf16x8 __attribute__((ext_vector_type(8)));
typedef float f32x4 __attribute__((ext_vector_type(4)));

static __device__ __forceinline__ unsigned cvt_pk_bf16(float a, float b) {
  unsigned r;
  asm("v_cvt_pk_bf16_f32 %0, %1, %2" : "=v"(r) : "v"(a), "v"(b));
  return r;  // lo16 = bf16(a), hi16 = bf16(b), RNE
}
// fp32 -> (hi bf16x4, lo bf16x4) with hi+lo ~ full precision
static __device__ __forceinline__ void split4_pk(float4 v, uint2& hi, uint2& lo) {
  hi.x = cvt_pk_bf16(v.x, v.y);
  hi.y = cvt_pk_bf16(v.z, v.w);
  float r0 = v.x - __uint_as_float(hi.x << 16);
  float r1 = v.y - __uint_as_float(hi.x & 0xFFFF0000u);
  float r2 = v.z - __uint_as_float(hi.y << 16);
  float r3 = v.w - __uint_as_float(hi.y & 0xFFFF0000u);
  lo.x = cvt_pk_bf16(r0, r1);
  lo.y = cvt_pk_bf16(r2, r3);
}
// dword offset of 16B unit u (0/1) of row r in a rows-of-8-dwords array,
// XOR-swizzled so stride-8 row reads spread across banks (both sides use it).
static __device__ __forceinline__ int swz8(int r, int u) {
  return r * 8 + ((u ^ ((r >> 2) & 1)) << 2);
}

// ---------------- Fused kernel: MFMA + in-block routing + weighted accumulate ----
// grid 1024; xcd = bx&7, slot = bx>>3; ng = xcd*32 + (slot>>2); bq = slot&3
// (all 4 bq blocks of an ng on one XCD -> W read once per XCD from L2/L3).
// block 512 = 8 waves; wave wv owns o = wv*4 .. wv*4+3, all 16 b of the bq.
// A = [W_hi|W_lo] (m=d, K=32 packed split), B = [x_hi],[x_lo] dup along K.
// LDS dword offsets (rows of 8 dwords, swizzled):
#define WAOFF 0       // 32 o * 32 rows (s*16+d) * 8 = 8192
#define XBOFF 8192    // 32 rows (s*16+b_local) * 8 = 256
#define HOFF  8448    // h[b_local][o]: 16 * 33 = 528
#define C2OFF 8976    // c2[o][b_local]: 32 * 17 = 544
#define LDSZ  9520    // 38.1 KB
__global__ __launch_bounds__(512, 6) void caps_fused_kernel(
    const float* __restrict__ x, const float* __restrict__ W,
    float* __restrict__ partial)
{
  const int bx = blockIdx.x;
  const int xcd = bx & 7, slot = bx >> 3;
  const int ng = xcd * 32 + (slot >> 2);
  const int bq = slot & 3;
  const int t = threadIdx.x;
  const int wv = t >> 6, l = t & 63;
  const int q = l >> 4, dq = l & 15, qh = q & 1, s_a = q >> 1;

  __shared__ __align__(16) float lds[LDSZ];
  float* WA  = lds + WAOFF;
  float* XB  = lds + XBOFF;
  float* hS  = lds + HOFF;
  float* c2S = lds + C2OFF;

  float sacc[4][4];
  #pragma unroll
  for (int oo = 0; oo < 4; ++oo)
    { sacc[oo][0] = 0.f; sacc[oo][1] = 0.f; sacc[oo][2] = 0.f; sacc[oo][3] = 0.f; }

  const int n0 = ng * 8;
  // staging decompositions: W chunk c covers o = c*8 + wv; (d, i4) from t
  const int wd = (t >> 2) & 15, wi4 = t & 3;
  const int wu = wi4 >> 1, wsub = (wi4 & 1) * 2;
  const int xb = t >> 2, xi4 = t & 3;          // x staging: t < 64 only
  const int xu = xi4 >> 1, xsub = (xi4 & 1) * 2;

  // initial global loads (full W[n]: 4 chunks of 8 o's; x: 16 b x 16 i)
  float4 wreg[4];
  #pragma unroll
  for (int c = 0; c < 4; ++c)
    wreg[c] = *(const float4*)(W + (size_t)n0 * 8192 + c * 2048 + 4 * t);
  float4 xreg = make_float4(0.f, 0.f, 0.f, 0.f);
  if (t < 64)
    xreg = *(const float4*)(x + (size_t)(bq * 16 + xb) * (NI * 16) + n0 * 16 + xi4 * 4);

  #pragma unroll 1
  for (int nn = 0; nn < 8; ++nn) {
    // ---- stage: cvt_pk split to bf16, swizzled LDS writes ----
    #pragma unroll
    for (int c = 0; c < 4; ++c) {
      uint2 hi, lo;
      split4_pk(wreg[c], hi, lo);
      const int rh = (c * 8 + wv) * 32 + wd;     // hi row (s=0)
      *(uint2*)&WA[swz8(rh, wu) + wsub] = hi;
      *(uint2*)&WA[swz8(rh + 16, wu) + wsub] = lo;
    }
    if (t < 64) {
      uint2 hi, lo;
      split4_pk(xreg, hi, lo);
      *(uint2*)&XB[swz8(xb, xu) + xsub] = hi;
      *(uint2*)&XB[swz8(16 + xb, xu) + xsub] = lo;
    }
    __syncthreads();   // sync1: LDS staged

    // ---- prefetch next n (overlaps MFMA + routing below) ----
    if (nn < 7) {
      const size_t nb = (size_t)(n0 + nn + 1);
      #pragma unroll
      for (int c = 0; c < 4; ++c)
        wreg[c] = *(const float4*)(W + nb * 8192 + c * 2048 + 4 * t);
      if (t < 64)
        xreg = *(const float4*)(x + (size_t)(bq * 16 + xb) * (NI * 16) + nb * 16 + xi4 * 4);
    }

    // ---- MFMA: D retained per o; h = row-sum(D) -> LDS ----
    f32x4 Dv[4];
    {
      bf16x8 B0 = *(const bf16x8*)&XB[swz8(dq, qh)];        // x_hi
      bf16x8 B1 = *(const bf16x8*)&XB[swz8(16 + dq, qh)];   // x_lo
      #pragma unroll
      for (int oo = 0; oo < 4; ++oo) {
        const int o = wv * 4 + oo;
        bf16x8 A = *(const bf16x8*)&WA[swz8(o * 32 + s_a * 16 + dq, qh)];
        f32x4 D = {0.f, 0.f, 0.f, 0.f};
        D = __builtin_amdgcn_mfma_f32_16x16x32_bf16(A, B0, D, 0, 0, 0);
        D = __builtin_amdgcn_mfma_f32_16x16x32_bf16(A, B1, D, 0, 0, 0);
        Dv[oo] = D;
        float hs = D[0] + D[1] + D[2] + D[3];   // sum over d within q-group
        hs += __shfl_xor(hs, 16);
        hs += __shfl_xor(hs, 32);               // sum over q
        if (q == 0) hS[dq * 33 + o] = hs;
      }
    }
    __syncthreads();   // sync2: h complete

    // ---- routing (proven math): one (b_local, o) per thread,
    //      softmax over o via 5-level xor-shuffle (o = lane bits 0..4) ----
    {
      const int bl = t >> 5, o = t & 31;
      const float h = hS[bl * 33 + o];
      const float b1 = h * 0.03125f;
      float mx = b1;
      mx = fmaxf(mx, __shfl_xor(mx, 1));  mx = fmaxf(mx, __shfl_xor(mx, 2));
      mx = fmaxf(mx, __shfl_xor(mx, 4));  mx = fmaxf(mx, __shfl_xor(mx, 8));
      mx = fmaxf(mx, __shfl_xor(mx, 16));
      const float e = __expf(b1 - mx);
      float S = e;
      S += __shfl_xor(S, 1); S += __shfl_xor(S, 2);
      S += __shfl_xor(S, 4); S += __shfl_xor(S, 8); S += __shfl_xor(S, 16);
      const float b2 = b1 + e * (1.0f / S) * h;
      float mx2 = b2;
      mx2 = fmaxf(mx2, __shfl_xor(mx2, 1));  mx2 = fmaxf(mx2, __shfl_xor(mx2, 2));
      mx2 = fmaxf(mx2, __shfl_xor(mx2, 4));  mx2 = fmaxf(mx2, __shfl_xor(mx2, 8));
      mx2 = fmaxf(mx2, __shfl_xor(mx2, 16));
      const float e2 = __expf(b2 - mx2);
      float S2 = e2;
      S2 += __shfl_xor(S2, 1); S2 += __shfl_xor(S2, 2);
      S2 += __shfl_xor(S2, 4); S2 += __shfl_xor(S2, 8); S2 += __shfl_xor(S2, 16);
      c2S[o * 17 + bl] = e2 * (1.0f / S2);
    }
    __syncthreads();   // sync3: c2 ready

    // ---- weighted accumulate from retained D (no second MFMA pass) ----
    #pragma unroll
    for (int oo = 0; oo < 4; ++oo) {
      const int o = wv * 4 + oo;
      const float c = c2S[o * 17 + dq];
      sacc[oo][0] += c * Dv[oo][0]; sacc[oo][1] += c * Dv[oo][1];
      sacc[oo][2] += c * Dv[oo][2]; sacc[oo][3] += c * Dv[oo][3];
    }
    // no sync needed: next stage writes WA/XB (last read before sync2);
    // c2S next written only after next sync2.
  }

  // ---- epilogue: gidx-major, block-contiguous (proven clean-WRITE layout) ----
  // partial[ng][b_global][cell], cell = o*16 + d, d = q*4 + r
  float* pb = partial + (size_t)ng * 32768
            + (size_t)(bq * 16 + dq) * 512 + q * 4;
  #pragma unroll
  for (int oo = 0; oo < 4; ++oo) {
    const int o = wv * 4 + oo;
    *(float4*)(pb + o * 16)
        = make_float4(sacc[oo][0], sacc[oo][1], sacc[oo][2], sacc[oo][3]);
  }
}

// ---------------- Kernel 2: reduce 256 group-partials + squash (unchanged) ----
__global__ __launch_bounds__(256) void caps_reduce_kernel(
    const float* __restrict__ partial, float* __restrict__ out)
{
  const int t = threadIdx.x;
  const int w4 = t >> 6, ln = t & 63;
  const int pair = blockIdx.x * 4 + w4;     // (b,o), 2048 total
  const int b = pair >> 5, o = pair & 31;
  const int d = ln & 15, cg = ln >> 4;
  const float* p = partial + (size_t)b * 512 + o * 16 + d;
  float s = 0.f;
  #pragma unroll 8
  for (int gg = cg; gg < 256; gg += 4) s += p[(size_t)gg * 32768];
  s += __shfl_xor(s, 16); s += __shfl_xor(s, 32);    // over cg
  float s2 = s * s;
  s2 += __shfl_xor(s2, 1); s2 += __shfl_xor(s2, 2);
  s2 += __shfl_xor(s2, 4); s2 += __shfl_xor(s2, 8);  // over d
  float scale = s2 / (1.0f + s2) / sqrtf(s2 + 1e-7f);
  if (ln < 16) out[(size_t)b * 512 + o * 16 + d] = scale * s;
}

extern "C" void kernel_launch(void* const* d_in, const int* in_sizes, int n_in,
                              void* d_out, int out_size, void* d_ws, size_t ws_size,
                              hipStream_t stream) {
  const float* x = (const float*)d_in[0];   // [64,2048,16]
  const float* W = (const float*)d_in[1];   // [1,2048,32,16,16]
  if (in_sizes[0] != 64 * 2048 * 16) { const float* tmp = x; x = W; W = tmp; }
  float* out = (float*)d_out;               // [64,32,16]

  float* partial = (float*)d_ws;            // 256*32768 f32 = 32 MB (gidx-major)

  caps_fused_kernel<<<1024, 512, 0, stream>>>(x, W, partial);
  caps_reduce_kernel<<<512, 256, 0, stream>>>(partial, out);
}

// Round 4
// 134.712 us; speedup vs baseline: 1.5833x; 1.2153x over previous
//
#include <hip/hip_runtime.h>
#include <cmath>

// CapsuleLayer routing, B=64, Ni=2048, Di=16, No=32, Do=16 (fp32 in/out).
// R8: fused plan with the register budget FIXED at the proven-clean (512,4)
// (R5 evidence: cap-128 -> zero spill traffic; R6/R7 caps of 64/85 both
// spilled accumulators to scratch and regressed). Keeps R6/R7's verified
// levers: XOR-swizzled pad-free LDS (bank conflicts 2.69M -> 0), cvt_pk
// bf16 staging, 4-way b-split on one XCD per n-group.
// New this round:
//  (a) 2 barriers per n-step (was 3): single-buffer software pipeline —
//      stage(n+1) LDS writes sit in the routing phase between syncA/syncB.
//      Order proof: MFMA reads(n) < syncA < stage writes(n+1) < syncB <
//      MFMA reads(n+1); hS writes(n) < syncA < routing reads(n) < syncB <
//      hS writes(n+1); c2S writes(n) < syncB < c2S reads(n) < syncA(n+1).
//  (b) 128 n-groups x 16 n (grid 512 = exactly 2 blocks/CU, one pass):
//      partial 33.5 -> 16.8 MB, reduce reads halved.

#define NI 2048
#define NGROUPS 128
#define NPER 16

typedef short bf16x8 __attribute__((ext_vector_type(8)));
typedef float f32x4 __attribute__((ext_vector_type(4)));

static __device__ __forceinline__ unsigned cvt_pk_bf16(float a, float b) {
  unsigned r;
  asm("v_cvt_pk_bf16_f32 %0, %1, %2" : "=v"(r) : "v"(a), "v"(b));
  return r;  // lo16 = bf16(a), hi16 = bf16(b), RNE
}
// fp32 -> (hi bf16x4, lo bf16x4) with hi+lo ~ full precision
static __device__ __forceinline__ void split4_pk(float4 v, uint2& hi, uint2& lo) {
  hi.x = cvt_pk_bf16(v.x, v.y);
  hi.y = cvt_pk_bf16(v.z, v.w);
  float r0 = v.x - __uint_as_float(hi.x << 16);
  float r1 = v.y - __uint_as_float(hi.x & 0xFFFF0000u);
  float r2 = v.z - __uint_as_float(hi.y << 16);
  float r3 = v.w - __uint_as_float(hi.y & 0xFFFF0000u);
  lo.x = cvt_pk_bf16(r0, r1);
  lo.y = cvt_pk_bf16(r2, r3);
}
// dword offset of 16B unit u (0/1) of row r in a rows-of-8-dwords array,
// XOR-swizzled so stride-8 row reads spread across banks (both sides use it).
static __device__ __forceinline__ int swz8(int r, int u) {
  return r * 8 + ((u ^ ((r >> 2) & 1)) << 2);
}

// ---------------- Fused kernel: MFMA + in-block routing + weighted accumulate ----
// grid 512; xcd = bx&7, slot = bx>>3 (0..63); ng = xcd*16 + (slot>>2); bq = slot&3
// (all 4 bq blocks of an ng on one XCD -> W read once per XCD from L2/L3).
// block 512 = 8 waves; wave wv owns o = wv*4 .. wv*4+3, all 16 b of the bq.
// A = [W_hi|W_lo] (m=d, K=32 packed split), B = [x_hi],[x_lo] dup along K.
// LDS dword offsets (rows of 8 dwords, swizzled):
#define WAOFF 0       // 32 o * 32 rows (s*16+d) * 8 = 8192
#define XBOFF 8192    // 32 rows (s*16+b_local) * 8 = 256
#define HOFF  8448    // h[b_local][o]: 16 * 33 = 528
#define C2OFF 8976    // c2[o][b_local]: 32 * 17 = 544
#define LDSZ  9520    // 38.1 KB
__global__ __launch_bounds__(512, 4) void caps_fused_kernel(
    const float* __restrict__ x, const float* __restrict__ W,
    float* __restrict__ partial)
{
  const int bx = blockIdx.x;
  const int xcd = bx & 7, slot = bx >> 3;
  const int ng = xcd * 16 + (slot >> 2);
  const int bq = slot & 3;
  const int t = threadIdx.x;
  const int wv = t >> 6, l = t & 63;
  const int q = l >> 4, dq = l & 15, qh = q & 1, s_a = q >> 1;

  __shared__ __align__(16) float lds[LDSZ];
  float* WA  = lds + WAOFF;
  float* XB  = lds + XBOFF;
  float* hS  = lds + HOFF;
  float* c2S = lds + C2OFF;

  float sacc[4][4];
  #pragma unroll
  for (int oo = 0; oo < 4; ++oo)
    { sacc[oo][0] = 0.f; sacc[oo][1] = 0.f; sacc[oo][2] = 0.f; sacc[oo][3] = 0.f; }

  const int n0 = ng * NPER;
  // staging decompositions: W chunk c covers o = c*8 + wv; (d, i4) from t
  const int wd = (t >> 2) & 15, wi4 = t & 3;
  const int wu = wi4 >> 1, wsub = (wi4 & 1) * 2;
  const int xb = t >> 2, xi4 = t & 3;          // x staging: t < 64 only
  const int xu = xi4 >> 1, xsub = (xi4 & 1) * 2;

  // ---- prologue: load + stage n0, then prefetch n0+1 ----
  float4 wreg[4];
  float4 xreg = make_float4(0.f, 0.f, 0.f, 0.f);
  #pragma unroll
  for (int c = 0; c < 4; ++c)
    wreg[c] = *(const float4*)(W + (size_t)n0 * 8192 + c * 2048 + 4 * t);
  if (t < 64)
    xreg = *(const float4*)(x + (size_t)(bq * 16 + xb) * (NI * 16) + n0 * 16 + xi4 * 4);

  #pragma unroll
  for (int c = 0; c < 4; ++c) {
    uint2 hi, lo;
    split4_pk(wreg[c], hi, lo);
    const int rh = (c * 8 + wv) * 32 + wd;
    *(uint2*)&WA[swz8(rh, wu) + wsub] = hi;
    *(uint2*)&WA[swz8(rh + 16, wu) + wsub] = lo;
  }
  if (t < 64) {
    uint2 hi, lo;
    split4_pk(xreg, hi, lo);
    *(uint2*)&XB[swz8(xb, xu) + xsub] = hi;
    *(uint2*)&XB[swz8(16 + xb, xu) + xsub] = lo;
  }
  __syncthreads();

  {
    const size_t nb = (size_t)(n0 + 1);
    #pragma unroll
    for (int c = 0; c < 4; ++c)
      wreg[c] = *(const float4*)(W + nb * 8192 + c * 2048 + 4 * t);
    if (t < 64)
      xreg = *(const float4*)(x + (size_t)(bq * 16 + xb) * (NI * 16) + nb * 16 + xi4 * 4);
  }

  #pragma unroll 1
  for (int nn = 0; nn < NPER; ++nn) {
    // ---- phase 1: MFMA from LDS (data nn); h = row-sum(D) -> hS ----
    f32x4 Dv[4];
    {
      bf16x8 B0 = *(const bf16x8*)&XB[swz8(dq, qh)];        // x_hi
      bf16x8 B1 = *(const bf16x8*)&XB[swz8(16 + dq, qh)];   // x_lo
      #pragma unroll
      for (int oo = 0; oo < 4; ++oo) {
        const int o = wv * 4 + oo;
        bf16x8 A = *(const bf16x8*)&WA[swz8(o * 32 + s_a * 16 + dq, qh)];
        f32x4 D = {0.f, 0.f, 0.f, 0.f};
        D = __builtin_amdgcn_mfma_f32_16x16x32_bf16(A, B0, D, 0, 0, 0);
        D = __builtin_amdgcn_mfma_f32_16x16x32_bf16(A, B1, D, 0, 0, 0);
        Dv[oo] = D;
        float hs = D[0] + D[1] + D[2] + D[3];   // sum over d within q-group
        hs += __shfl_xor(hs, 16);
        hs += __shfl_xor(hs, 32);               // sum over q
        if (q == 0) hS[dq * 33 + o] = hs;
      }
    }
    __syncthreads();   // syncA: hS ready; MFMA reads of WA/XB(nn) complete

    // ---- phase 2a: stage data nn+1 into WA/XB (pipelined, single buffer) ----
    if (nn < NPER - 1) {
      #pragma unroll
      for (int c = 0; c < 4; ++c) {
        uint2 hi, lo;
        split4_pk(wreg[c], hi, lo);
        const int rh = (c * 8 + wv) * 32 + wd;
        *(uint2*)&WA[swz8(rh, wu) + wsub] = hi;
        *(uint2*)&WA[swz8(rh + 16, wu) + wsub] = lo;
      }
      if (t < 64) {
        uint2 hi, lo;
        split4_pk(xreg, hi, lo);
        *(uint2*)&XB[swz8(xb, xu) + xsub] = hi;
        *(uint2*)&XB[swz8(16 + xb, xu) + xsub] = lo;
      }
    }

    // ---- phase 2b: routing (proven math): one (b_local, o) per thread,
    //      softmax over o via 5-level xor-shuffle (o = lane bits 0..4) ----
    {
      const int bl = t >> 5, o = t & 31;
      const float h = hS[bl * 33 + o];
      const float b1 = h * 0.03125f;
      float mx = b1;
      mx = fmaxf(mx, __shfl_xor(mx, 1));  mx = fmaxf(mx, __shfl_xor(mx, 2));
      mx = fmaxf(mx, __shfl_xor(mx, 4));  mx = fmaxf(mx, __shfl_xor(mx, 8));
      mx = fmaxf(mx, __shfl_xor(mx, 16));
      const float e = __expf(b1 - mx);
      float S = e;
      S += __shfl_xor(S, 1); S += __shfl_xor(S, 2);
      S += __shfl_xor(S, 4); S += __shfl_xor(S, 8); S += __shfl_xor(S, 16);
      const float b2 = b1 + e * (1.0f / S) * h;
      float mx2 = b2;
      mx2 = fmaxf(mx2, __shfl_xor(mx2, 1));  mx2 = fmaxf(mx2, __shfl_xor(mx2, 2));
      mx2 = fmaxf(mx2, __shfl_xor(mx2, 4));  mx2 = fmaxf(mx2, __shfl_xor(mx2, 8));
      mx2 = fmaxf(mx2, __shfl_xor(mx2, 16));
      const float e2 = __expf(b2 - mx2);
      float S2 = e2;
      S2 += __shfl_xor(S2, 1); S2 += __shfl_xor(S2, 2);
      S2 += __shfl_xor(S2, 4); S2 += __shfl_xor(S2, 8); S2 += __shfl_xor(S2, 16);
      c2S[o * 17 + bl] = e2 * (1.0f / S2);
    }

    // ---- phase 2c: issue global prefetch for nn+2 ----
    if (nn < NPER - 2) {
      const size_t nb = (size_t)(n0 + nn + 2);
      #pragma unroll
      for (int c = 0; c < 4; ++c)
        wreg[c] = *(const float4*)(W + nb * 8192 + c * 2048 + 4 * t);
      if (t < 64)
        xreg = *(const float4*)(x + (size_t)(bq * 16 + xb) * (NI * 16) + nb * 16 + xi4 * 4);
    }
    __syncthreads();   // syncB: c2S ready; WA/XB(nn+1) staged

    // ---- phase 3: weighted accumulate from retained D ----
    #pragma unroll
    for (int oo = 0; oo < 4; ++oo) {
      const int o = wv * 4 + oo;
      const float c = c2S[o * 17 + dq];
      sacc[oo][0] += c * Dv[oo][0]; sacc[oo][1] += c * Dv[oo][1];
      sacc[oo][2] += c * Dv[oo][2]; sacc[oo][3] += c * Dv[oo][3];
    }
    // c2S reads here precede the next syncA; next c2S writes come after it.
  }

  // ---- epilogue: gidx-major, block-contiguous (proven clean-WRITE layout) ----
  // partial[ng][b_global][cell], cell = o*16 + d, d = q*4 + r
  float* pb = partial + (size_t)ng * 32768
            + (size_t)(bq * 16 + dq) * 512 + q * 4;
  #pragma unroll
  for (int oo = 0; oo < 4; ++oo) {
    const int o = wv * 4 + oo;
    *(float4*)(pb + o * 16)
        = make_float4(sacc[oo][0], sacc[oo][1], sacc[oo][2], sacc[oo][3]);
  }
}

// ---------------- Kernel 2: reduce 128 group-partials + squash ----------------
__global__ __launch_bounds__(256) void caps_reduce_kernel(
    const float* __restrict__ partial, float* __restrict__ out)
{
  const int t = threadIdx.x;
  const int w4 = t >> 6, ln = t & 63;
  const int pair = blockIdx.x * 4 + w4;     // (b,o), 2048 total
  const int b = pair >> 5, o = pair & 31;
  const int d = ln & 15, cg = ln >> 4;
  const float* p = partial + (size_t)b * 512 + o * 16 + d;
  float s = 0.f;
  #pragma unroll 8
  for (int gg = cg; gg < NGROUPS; gg += 4) s += p[(size_t)gg * 32768];
  s += __shfl_xor(s, 16); s += __shfl_xor(s, 32);    // over cg
  float s2 = s * s;
  s2 += __shfl_xor(s2, 1); s2 += __shfl_xor(s2, 2);
  s2 += __shfl_xor(s2, 4); s2 += __shfl_xor(s2, 8);  // over d
  float scale = s2 / (1.0f + s2) / sqrtf(s2 + 1e-7f);
  if (ln < 16) out[(size_t)b * 512 + o * 16 + d] = scale * s;
}

extern "C" void kernel_launch(void* const* d_in, const int* in_sizes, int n_in,
                              void* d_out, int out_size, void* d_ws, size_t ws_size,
                              hipStream_t stream) {
  const float* x = (const float*)d_in[0];   // [64,2048,16]
  const float* W = (const float*)d_in[1];   // [1,2048,32,16,16]
  if (in_sizes[0] != 64 * 2048 * 16) { const float* tmp = x; x = W; W = tmp; }
  float* out = (float*)d_out;               // [64,32,16]

  float* partial = (float*)d_ws;            // 128*32768 f32 = 16.8 MB (gidx-major)

  caps_fused_kernel<<<512, 512, 0, stream>>>(x, W, partial);
  caps_reduce_kernel<<<512, 256, 0, stream>>>(partial, out);
}

// Round 5
// 124.968 us; speedup vs baseline: 1.7068x; 1.0780x over previous
//
#include <hip/hip_runtime.h>
#include <cmath>

// CapsuleLayer routing, B=64, Ni=2048, Di=16, No=32, Do=16 (fp32 in/out).
// R9: recombination. R8 post-mortem: 4-way b-split doubled block-n-iterations
// (8192 vs 4096) -> staging/routing/barrier overhead x2; R5's 2-way split at
// 42.4us beat R8's 54.4us despite worse per-iter code. So: R5 geometry
// (256 ng x 2 bh, 8 waves = 2 b-tiles x 4 o-quads, 8 o/wave) + ALL verified
// levers:
//  - pad-free XOR-swizzled LDS (R6: conflicts 2.69M -> 0), 43.3 KB
//  - v_cvt_pk_bf16_f32 staging (R6)
//  - 2-barrier single-buffer pipeline, prefetch 2 ahead (R8, traffic-clean)
//  - (512,4) launch bounds (R5/R8: the only proven spill-free cap)
// Order proof (single buffer): MFMA reads(n) < syncA < stage writes(n+1) <
// syncB < MFMA reads(n+1); hS wr(n) < syncA < rd(n) < syncB < wr(n+1);
// c2S wr(n) < syncB < rd(n) < syncA(n+1) < wr(n+1).

#define NI 2048
#define NGROUPS 256
#define NPER 8

typedef short bf16x8 __attribute__((ext_vector_type(8)));
typedef float f32x4 __attribute__((ext_vector_type(4)));

static __device__ __forceinline__ unsigned cvt_pk_bf16(float a, float b) {
  unsigned r;
  asm("v_cvt_pk_bf16_f32 %0, %1, %2" : "=v"(r) : "v"(a), "v"(b));
  return r;  // lo16 = bf16(a), hi16 = bf16(b), RNE
}
// fp32 -> (hi bf16x4, lo bf16x4) with hi+lo ~ full precision
static __device__ __forceinline__ void split4_pk(float4 v, uint2& hi, uint2& lo) {
  hi.x = cvt_pk_bf16(v.x, v.y);
  hi.y = cvt_pk_bf16(v.z, v.w);
  float r0 = v.x - __uint_as_float(hi.x << 16);
  float r1 = v.y - __uint_as_float(hi.x & 0xFFFF0000u);
  float r2 = v.z - __uint_as_float(hi.y << 16);
  float r3 = v.w - __uint_as_float(hi.y & 0xFFFF0000u);
  lo.x = cvt_pk_bf16(r0, r1);
  lo.y = cvt_pk_bf16(r2, r3);
}
// dword offset of 16B unit u (0/1) of row r in a rows-of-8-dwords array,
// XOR-swizzled so stride-8 row reads spread across banks (both sides use it).
static __device__ __forceinline__ int swz8(int r, int u) {
  return r * 8 + ((u ^ ((r >> 2) & 1)) << 2);
}

// ---------------- Fused kernel: MFMA + in-block routing + weighted accumulate ----
// grid 512; xcd = bx&7, slot = bx>>3 (0..63); ng = xcd*32 + (slot>>1); bh = slot&1
// (both bh blocks of an ng on one XCD -> W read once per XCD from L2/L3).
// block 512 = 8 waves = (bt = wv&1: 16-b tile of the 32-b half) x (oq = wv>>1:
// o-octet). Wave: o = oq*8 .. oq*8+7, b = bt*16 .. +15.
// A = [W_hi|W_lo] (m=d, K=32 packed split), B = [x_hi],[x_lo] dup along K.
// LDS dword offsets (rows of 8 dwords, swizzled):
#define WAOFF 0        // 32 o * 32 rows (s*16+d) * 8 = 8192
#define XBOFF 8192     // 64 rows (s*32 + b_local) * 8 = 512
#define HOFF  8704     // h[b_local][o]: 32 * 33 = 1056
#define C2OFF 9760     // c2[o][b_local]: 32 * 33 = 1056
#define LDSZ  10816    // 43.3 KB
__global__ __launch_bounds__(512, 4) void caps_fused_kernel(
    const float* __restrict__ x, const float* __restrict__ W,
    float* __restrict__ partial)
{
  const int bx = blockIdx.x;
  const int xcd = bx & 7, slot = bx >> 3;
  const int ng = xcd * 32 + (slot >> 1);
  const int bh = slot & 1;
  const int t = threadIdx.x;
  const int wv = t >> 6, l = t & 63;
  const int q = l >> 4, dq = l & 15, qh = q & 1, s_a = q >> 1;
  const int bt = wv & 1, oq = wv >> 1;

  __shared__ __align__(16) float lds[LDSZ];
  float* WA  = lds + WAOFF;
  float* XB  = lds + XBOFF;
  float* hS  = lds + HOFF;
  float* c2S = lds + C2OFF;

  float sacc[8][4];
  #pragma unroll
  for (int oo = 0; oo < 8; ++oo)
    { sacc[oo][0] = 0.f; sacc[oo][1] = 0.f; sacc[oo][2] = 0.f; sacc[oo][3] = 0.f; }

  const int n0 = ng * NPER;
  // staging decompositions: W chunk c covers o = c*8 + wv; (d, i4) from t
  const int wd = (t >> 2) & 15, wi4 = t & 3;
  const int wu = wi4 >> 1, wsub = (wi4 & 1) * 2;
  const int xb = t >> 2, xi4 = t & 3;          // x staging: t < 128 (32 b)
  const int xu = xi4 >> 1, xsub = (xi4 & 1) * 2;

  // ---- prologue: load + stage n0, then prefetch n0+1 ----
  float4 wreg[4];
  float4 xreg = make_float4(0.f, 0.f, 0.f, 0.f);
  #pragma unroll
  for (int c = 0; c < 4; ++c)
    wreg[c] = *(const float4*)(W + (size_t)n0 * 8192 + c * 2048 + 4 * t);
  if (t < 128)
    xreg = *(const float4*)(x + (size_t)(bh * 32 + xb) * (NI * 16) + n0 * 16 + xi4 * 4);

  #pragma unroll
  for (int c = 0; c < 4; ++c) {
    uint2 hi, lo;
    split4_pk(wreg[c], hi, lo);
    const int rh = (c * 8 + wv) * 32 + wd;
    *(uint2*)&WA[swz8(rh, wu) + wsub] = hi;
    *(uint2*)&WA[swz8(rh + 16, wu) + wsub] = lo;
  }
  if (t < 128) {
    uint2 hi, lo;
    split4_pk(xreg, hi, lo);
    *(uint2*)&XB[swz8(xb, xu) + xsub] = hi;
    *(uint2*)&XB[swz8(32 + xb, xu) + xsub] = lo;
  }
  __syncthreads();

  {
    const size_t nb = (size_t)(n0 + 1);
    #pragma unroll
    for (int c = 0; c < 4; ++c)
      wreg[c] = *(const float4*)(W + nb * 8192 + c * 2048 + 4 * t);
    if (t < 128)
      xreg = *(const float4*)(x + (size_t)(bh * 32 + xb) * (NI * 16) + nb * 16 + xi4 * 4);
  }

  #pragma unroll 1
  for (int nn = 0; nn < NPER; ++nn) {
    // ---- phase 1: MFMA from LDS (data nn); h = row-sum(D) -> hS ----
    f32x4 Dv[8];
    {
      bf16x8 B0 = *(const bf16x8*)&XB[swz8(bt * 16 + dq, qh)];        // x_hi
      bf16x8 B1 = *(const bf16x8*)&XB[swz8(32 + bt * 16 + dq, qh)];   // x_lo
      #pragma unroll
      for (int oo = 0; oo < 8; ++oo) {
        const int o = oq * 8 + oo;
        bf16x8 A = *(const bf16x8*)&WA[swz8(o * 32 + s_a * 16 + dq, qh)];
        f32x4 D = {0.f, 0.f, 0.f, 0.f};
        D = __builtin_amdgcn_mfma_f32_16x16x32_bf16(A, B0, D, 0, 0, 0);
        D = __builtin_amdgcn_mfma_f32_16x16x32_bf16(A, B1, D, 0, 0, 0);
        Dv[oo] = D;
        float hs = D[0] + D[1] + D[2] + D[3];   // sum over d within q-group
        hs += __shfl_xor(hs, 16);
        hs += __shfl_xor(hs, 32);               // sum over q
        if (q == 0) hS[(bt * 16 + dq) * 33 + o] = hs;
      }
    }
    __syncthreads();   // syncA: hS ready; MFMA reads of WA/XB(nn) complete

    // ---- phase 2a: stage data nn+1 into WA/XB (pipelined, single buffer) ----
    if (nn < NPER - 1) {
      #pragma unroll
      for (int c = 0; c < 4; ++c) {
        uint2 hi, lo;
        split4_pk(wreg[c], hi, lo);
        const int rh = (c * 8 + wv) * 32 + wd;
        *(uint2*)&WA[swz8(rh, wu) + wsub] = hi;
        *(uint2*)&WA[swz8(rh + 16, wu) + wsub] = lo;
      }
      if (t < 128) {
        uint2 hi, lo;
        split4_pk(xreg, hi, lo);
        *(uint2*)&XB[swz8(xb, xu) + xsub] = hi;
        *(uint2*)&XB[swz8(32 + xb, xu) + xsub] = lo;
      }
    }

    // ---- phase 2b: routing (R5-proven): thread (bl = t>>4, op = t&15)
    //      handles o = op and op+16; softmax reduce via 16-lane shuffles ----
    {
      const int bl = t >> 4, op = t & 15;
      const float h0 = hS[bl * 33 + op];
      const float h1 = hS[bl * 33 + op + 16];
      const float b10 = h0 * 0.03125f, b11 = h1 * 0.03125f;
      float mx = fmaxf(b10, b11);
      mx = fmaxf(mx, __shfl_xor(mx, 1)); mx = fmaxf(mx, __shfl_xor(mx, 2));
      mx = fmaxf(mx, __shfl_xor(mx, 4)); mx = fmaxf(mx, __shfl_xor(mx, 8));
      const float e0 = __expf(b10 - mx), e1 = __expf(b11 - mx);
      float S = e0 + e1;
      S += __shfl_xor(S, 1); S += __shfl_xor(S, 2);
      S += __shfl_xor(S, 4); S += __shfl_xor(S, 8);
      const float inv = 1.0f / S;
      const float b20 = b10 + e0 * inv * h0, b21 = b11 + e1 * inv * h1;
      float mx2 = fmaxf(b20, b21);
      mx2 = fmaxf(mx2, __shfl_xor(mx2, 1)); mx2 = fmaxf(mx2, __shfl_xor(mx2, 2));
      mx2 = fmaxf(mx2, __shfl_xor(mx2, 4)); mx2 = fmaxf(mx2, __shfl_xor(mx2, 8));
      const float e20 = __expf(b20 - mx2), e21 = __expf(b21 - mx2);
      float S2 = e20 + e21;
      S2 += __shfl_xor(S2, 1); S2 += __shfl_xor(S2, 2);
      S2 += __shfl_xor(S2, 4); S2 += __shfl_xor(S2, 8);
      const float inv2 = 1.0f / S2;
      c2S[op * 33 + bl] = e20 * inv2;
      c2S[(op + 16) * 33 + bl] = e21 * inv2;
    }

    // ---- phase 2c: issue global prefetch for nn+2 ----
    if (nn < NPER - 2) {
      const size_t nb = (size_t)(n0 + nn + 2);
      #pragma unroll
      for (int c = 0; c < 4; ++c)
        wreg[c] = *(const float4*)(W + nb * 8192 + c * 2048 + 4 * t);
      if (t < 128)
        xreg = *(const float4*)(x + (size_t)(bh * 32 + xb) * (NI * 16) + nb * 16 + xi4 * 4);
    }
    __syncthreads();   // syncB: c2S ready; WA/XB(nn+1) staged

    // ---- phase 3: weighted accumulate from retained D ----
    #pragma unroll
    for (int oo = 0; oo < 8; ++oo) {
      const int o = oq * 8 + oo;
      const float c = c2S[o * 33 + bt * 16 + dq];
      sacc[oo][0] += c * Dv[oo][0]; sacc[oo][1] += c * Dv[oo][1];
      sacc[oo][2] += c * Dv[oo][2]; sacc[oo][3] += c * Dv[oo][3];
    }
    // c2S reads here precede the next syncA; next c2S writes come after it.
  }

  // ---- epilogue: gidx-major, block-contiguous (proven clean-WRITE layout) ----
  // partial[ng][b_global][cell], cell = o*16 + d, d = q*4 + r
  float* pb = partial + (size_t)ng * 32768
            + (size_t)(bh * 32 + bt * 16 + dq) * 512 + q * 4;
  #pragma unroll
  for (int oo = 0; oo < 8; ++oo) {
    const int o = oq * 8 + oo;
    *(float4*)(pb + o * 16)
        = make_float4(sacc[oo][0], sacc[oo][1], sacc[oo][2], sacc[oo][3]);
  }
}

// ---------------- Kernel 2: reduce 256 group-partials + squash ----------------
__global__ __launch_bounds__(256) void caps_reduce_kernel(
    const float* __restrict__ partial, float* __restrict__ out)
{
  const int t = threadIdx.x;
  const int w4 = t >> 6, ln = t & 63;
  const int pair = blockIdx.x * 4 + w4;     // (b,o), 2048 total
  const int b = pair >> 5, o = pair & 31;
  const int d = ln & 15, cg = ln >> 4;
  const float* p = partial + (size_t)b * 512 + o * 16 + d;
  float s = 0.f;
  #pragma unroll 8
  for (int gg = cg; gg < NGROUPS; gg += 4) s += p[(size_t)gg * 32768];
  s += __shfl_xor(s, 16); s += __shfl_xor(s, 32);    // over cg
  float s2 = s * s;
  s2 += __shfl_xor(s2, 1); s2 += __shfl_xor(s2, 2);
  s2 += __shfl_xor(s2, 4); s2 += __shfl_xor(s2, 8);  // over d
  float scale = s2 / (1.0f + s2) / sqrtf(s2 + 1e-7f);
  if (ln < 16) out[(size_t)b * 512 + o * 16 + d] = scale * s;
}

extern "C" void kernel_launch(void* const* d_in, const int* in_sizes, int n_in,
                              void* d_out, int out_size, void* d_ws, size_t ws_size,
                              hipStream_t stream) {
  const float* x = (const float*)d_in[0];   // [64,2048,16]
  const float* W = (const float*)d_in[1];   // [1,2048,32,16,16]
  if (in_sizes[0] != 64 * 2048 * 16) { const float* tmp = x; x = W; W = tmp; }
  float* out = (float*)d_out;               // [64,32,16]

  float* partial = (float*)d_ws;            // 256*32768 f32 = 33.5 MB (gidx-major)

  caps_fused_kernel<<<512, 512, 0, stream>>>(x, W, partial);
  caps_reduce_kernel<<<512, 256, 0, stream>>>(partial, out);
}